// Round 1
// baseline (291.915 us; speedup 1.0000x reference)
//
#include <hip/hip_runtime.h>
#include <hip/hip_bf16.h>
#include <stdint.h>

#define BATCH   65536
#define UNITS   256
#define KDIM    512
#define BM      64
#define BN      64
#define BK      64
#define NCHUNK  (KDIM / BK)    // 8
#define SMEM_BYTES 81920       // A: 2*8K, B: 2*32K

using f32x16 = __attribute__((ext_vector_type(16))) float;
using bf16x8 = __attribute__((ext_vector_type(8))) short;

__device__ __forceinline__ short f2bf(float f) {
  union { float f; unsigned u; } v; v.f = f;
  unsigned r = v.u + 0x7FFFu + ((v.u >> 16) & 1u);   // RNE
  return (short)(r >> 16);
}
__device__ __forceinline__ float bf2f(short s) {
  union { float f; unsigned u; } v; v.u = ((unsigned)(unsigned short)s) << 16;
  return v.f;
}

__device__ __forceinline__ void gload_lds16(const void* gsrc, void* ldst) {
  __builtin_amdgcn_global_load_lds(
      (const __attribute__((address_space(1))) void*)gsrc,
      (__attribute__((address_space(3))) void*)ldst,
      16, 0, 0);
}

// ---- prepass: W_g fp32 [512][256] -> Wt bf16 [4][256][512]  (n-major, k contiguous)
__global__ void cvt_weights(const float* __restrict__ Wf, const float* __restrict__ Wi,
                            const float* __restrict__ Wc, const float* __restrict__ Wo,
                            short* __restrict__ Wt) {
  int idx = blockIdx.x * 256 + threadIdx.x;   // 0 .. 4*256*512-1
  int g   = idx >> 17;
  int rem = idx & 131071;
  int n   = rem >> 9;
  int k   = rem & 511;
  const float* W = (g == 0) ? Wf : (g == 1) ? Wi : (g == 2) ? Wc : Wo;
  Wt[idx] = f2bf(W[k * 256 + n]);
}

// ---- fused LSTM cell ----
// block: 256 threads = 4 waves; wave w owns gate w over a 64x64 output tile.
// LDS chunk layout (A and per-gate B identical): [kg 0..7][row 0..63][16B = 8 bf16]
__global__ __launch_bounds__(256, 2) void lstm_fused(
    const float* __restrict__ x, const float* __restrict__ hprev,
    const float* __restrict__ cprev, const short* __restrict__ Wt,
    const float* __restrict__ bfp, const float* __restrict__ bip,
    const float* __restrict__ bcp, const float* __restrict__ bop,
    float* __restrict__ hout, float* __restrict__ cout)
{
  extern __shared__ __align__(16) char smem[];
  const int tid  = threadIdx.x;
  const int wave = tid >> 6;
  const int lane = tid & 63;
  const int la   = lane & 31;
  const int hh   = lane >> 5;

  // XCD-bijective swizzle: nwg=4096, %8==0. Same M-tile's 4 N-tiles land on one XCD.
  int bid = blockIdx.x;
  int wg  = (bid & 7) * 512 + (bid >> 3);
  const int m0 = (wg >> 2) * BM;
  const int n0 = (wg & 3)  * BN;

  const int g = wave;                                   // gate: 0=f 1=i 2=c~ 3=o
  const short* WtG = Wt + ((size_t)(g * UNITS + n0)) * KDIM;

  f32x16 acc[2][2] = {};

  const int arow = tid >> 2;     // 0..63
  const int akg4 = tid & 3;      // kg quarter

  auto stageA = [&](int chunk, int buf) {
    const float* base = (chunk < 4) ? x : hprev;
    const int kb = (chunk & 3) * 64;
    char* Abuf = smem + buf * 8192;
    const float* rowp = base + (size_t)(m0 + arow) * 256 + kb;
#pragma unroll
    for (int j = 0; j < 2; ++j) {
      int kg = akg4 + j * 4;
      const float* src = rowp + kg * 8;
      float4 v0 = *(const float4*)(src);
      float4 v1 = *(const float4*)(src + 4);
      bf16x8 b;
      b[0] = f2bf(v0.x); b[1] = f2bf(v0.y); b[2] = f2bf(v0.z); b[3] = f2bf(v0.w);
      b[4] = f2bf(v1.x); b[5] = f2bf(v1.y); b[6] = f2bf(v1.z); b[7] = f2bf(v1.w);
      *(bf16x8*)(Abuf + kg * 1024 + arow * 16) = b;
    }
  };

  auto stageB = [&](int chunk, int buf) {
    char* Bbuf = smem + 16384 + buf * 32768 + g * 8192;   // wave-uniform
    const short* src0 = WtG + (size_t)lane * KDIM + chunk * BK;  // per-lane global
#pragma unroll
    for (int i = 0; i < 8; ++i) {
      // HW writes lane l at base + l*16 -> LDS (kg=i, n=lane)
      gload_lds16(src0 + i * 8, Bbuf + i * 1024);
    }
  };

  auto compute = [&](int buf) {
    const char* Abuf = smem + buf * 8192;
    const char* Bbuf = smem + 16384 + buf * 32768 + g * 8192;
#pragma unroll
    for (int ks = 0; ks < 4; ++ks) {
      const int off = (2 * ks + hh) * 1024 + la * 16;
      bf16x8 a0 = *(const bf16x8*)(Abuf + off);
      bf16x8 a1 = *(const bf16x8*)(Abuf + off + 512);
      bf16x8 b0 = *(const bf16x8*)(Bbuf + off);
      bf16x8 b1 = *(const bf16x8*)(Bbuf + off + 512);
      acc[0][0] = __builtin_amdgcn_mfma_f32_32x32x16_bf16(a0, b0, acc[0][0], 0, 0, 0);
      acc[0][1] = __builtin_amdgcn_mfma_f32_32x32x16_bf16(a0, b1, acc[0][1], 0, 0, 0);
      acc[1][0] = __builtin_amdgcn_mfma_f32_32x32x16_bf16(a1, b0, acc[1][0], 0, 0, 0);
      acc[1][1] = __builtin_amdgcn_mfma_f32_32x32x16_bf16(a1, b1, acc[1][1], 0, 0, 0);
    }
  };

  // ---- pipelined K loop ----
  stageB(0, 0);
  stageA(0, 0);
  __syncthreads();
  int buf = 0;
  for (int c = 0; c < NCHUNK; ++c) {
    if (c + 1 < NCHUNK) {        // issue next-chunk staging before compute
      stageB(c + 1, buf ^ 1);
      stageA(c + 1, buf ^ 1);
    }
    compute(buf);
    __syncthreads();             // drains vmcnt/lgkmcnt, flips buffer safely
    buf ^= 1;
  }

  // ---- epilogue: bias + activation -> LDS exchange (bf16 [4][64][68]) ----
  const float* bptr = (g == 0) ? bfp : (g == 1) ? bip : (g == 2) ? bcp : bop;
  const float bias0 = bptr[n0 + la];
  const float bias1 = bptr[n0 + 32 + la];
  short* G = (short*)smem;
#pragma unroll
  for (int mi = 0; mi < 2; ++mi)
#pragma unroll
    for (int ni = 0; ni < 2; ++ni) {
      const float bias = ni ? bias1 : bias0;
#pragma unroll
      for (int r = 0; r < 16; ++r) {
        int row = (r & 3) + 8 * (r >> 2) + 4 * hh + mi * 32;   // verified C/D map
        int col = la + ni * 32;
        float v = acc[mi][ni][r] + bias;
        float a;
        if (g == 2) a = 1.f - 2.f / (__expf(2.f * v) + 1.f);   // tanh, no-NaN form
        else        a = 1.f / (1.f + __expf(-v));              // sigmoid
        G[(g * 64 + row) * 68 + col] = f2bf(a);
      }
    }
  __syncthreads();

  // ---- combine + store (coalesced) ----
#pragma unroll
  for (int it = 0; it < 16; ++it) {
    int idx = tid + it * 256;
    int row = idx >> 6, col = idx & 63;
    float fg = bf2f(G[(0 * 64 + row) * 68 + col]);
    float ig = bf2f(G[(1 * 64 + row) * 68 + col]);
    float cg = bf2f(G[(2 * 64 + row) * 68 + col]);
    float og = bf2f(G[(3 * 64 + row) * 68 + col]);
    size_t gi = (size_t)(m0 + row) * 256 + (n0 + col);
    float cp = cprev[gi];
    float cnew = fg * cp + ig * cg;
    float hnew = og * (1.f - 2.f / (__expf(2.f * cnew) + 1.f));
    hout[gi] = hnew;
    cout[gi] = cnew;
  }
}

extern "C" void kernel_launch(void* const* d_in, const int* in_sizes, int n_in,
                              void* d_out, int out_size, void* d_ws, size_t ws_size,
                              hipStream_t stream) {
  const float* x     = (const float*)d_in[0];
  const float* hprev = (const float*)d_in[1];
  const float* cprev = (const float*)d_in[2];
  const float* Wf    = (const float*)d_in[3];
  const float* Wi    = (const float*)d_in[4];
  const float* Wc    = (const float*)d_in[5];
  const float* Wo    = (const float*)d_in[6];
  const float* bfp   = (const float*)d_in[7];
  const float* bip   = (const float*)d_in[8];
  const float* bcp   = (const float*)d_in[9];
  const float* bop   = (const float*)d_in[10];
  float* out = (float*)d_out;
  short* Wt  = (short*)d_ws;     // 4*256*512 bf16 = 1 MB scratch

  cvt_weights<<<2048, 256, 0, stream>>>(Wf, Wi, Wc, Wo, Wt);

  lstm_fused<<<dim3(4096), dim3(256), SMEM_BYTES, stream>>>(
      x, hprev, cprev, Wt, bfp, bip, bcp, bop,
      out, out + (size_t)BATCH * UNITS);
}

// Round 2
// 160.780 us; speedup vs baseline: 1.8156x; 1.8156x over previous
//
#include <hip/hip_runtime.h>
#include <stdint.h>

#define BATCH   65536
#define UNITS   256
#define KDIM    512
#define BM      64
#define BN      64
#define NCHUNK  8
#define GPAD    72                     // shorts per row in gate-exchange buffer
#define SMEM_BYTES 36864               // max(2*8192 A dbuf, 4*64*GPAD*2 = 36864)

using f32x16 = __attribute__((ext_vector_type(16))) float;
using bf16x8 = __attribute__((ext_vector_type(8))) short;

__device__ __forceinline__ short f2bf(float f) {
  union { float f; unsigned u; } v; v.f = f;
  unsigned r = v.u + 0x7FFFu + ((v.u >> 16) & 1u);   // RNE
  return (short)(r >> 16);
}
__device__ __forceinline__ float bf2f(short s) {
  union { float f; unsigned u; } v; v.u = ((unsigned)(unsigned short)s) << 16;
  return v.f;
}

// ---- prepass: W_g fp32 [512][256] -> Wt bf16 tiled [g][nb][c][kg][n][k8]
// (the exact B-fragment image: a wave's 16B/lane loads are contiguous)
__global__ void cvt_weights(const float* __restrict__ Wf, const float* __restrict__ Wi,
                            const float* __restrict__ Wc, const float* __restrict__ Wo,
                            short* __restrict__ Wt) {
  int idx = blockIdx.x * 256 + threadIdx.x;          // 0 .. 4*512*256-1
  int g   = idx >> 17;
  int k   = (idx >> 8) & 511;                        // coalesced read: col = tid
  int col = idx & 255;
  const float* W = (g == 0) ? Wf : (g == 1) ? Wi : (g == 2) ? Wc : Wo;
  float val = W[k * 256 + col];
  int nb = col >> 6, n = col & 63;
  int c = k >> 6, kg = (k >> 3) & 7, k8 = k & 7;
  int out = ((((g * 4 + nb) * 8 + c) * 8 + kg) * 64 + n) * 8 + k8;
  Wt[out] = f2bf(val);
}

// ---- fused LSTM cell ----
// 4 waves/block, wave = gate. A (64 rows x 64k bf16) double-buffered in LDS.
// B fragments read directly from L2 (pre-tiled Wt), no LDS for B.
__global__ __launch_bounds__(256, 3) void lstm_fused(
    const float* __restrict__ x, const float* __restrict__ hprev,
    const float* __restrict__ cprev, const short* __restrict__ Wt,
    const float* __restrict__ bfp, const float* __restrict__ bip,
    const float* __restrict__ bcp, const float* __restrict__ bop,
    float* __restrict__ hout, float* __restrict__ cout)
{
  extern __shared__ __align__(16) char smem[];
  const int tid  = threadIdx.x;
  const int g    = tid >> 6;           // wave = gate
  const int lane = tid & 63;
  const int la   = lane & 31;
  const int hh   = lane >> 5;

  // XCD swizzle: 4096 blocks, 8 XCDs; 4 N-tiles of one M-tile -> same XCD
  int bid = blockIdx.x;
  int wg  = (bid & 7) * 512 + (bid >> 3);
  const int m0 = (wg >> 2) * BM;
  const int nb = wg & 3;
  const int n0 = nb * BN;

  // per-(gate,nb) tiled weights; per-lane fragment base (2x512B segments)
  const short* Bbase = Wt + ((size_t)(g * 4 + nb)) * 32768 + hh * 512 + la * 8;

  f32x16 acc[2][2] = {};

  const int arow = tid >> 2;           // 0..63
  const int q    = tid & 3;            // k-quad
  const int slotW = (arow ^ (q << 2)) & 63;   // XOR-swizzled LDS slot (write)

  auto ldA = [&](int c, float4* v) {
    const float* base = (c < 4) ? x : hprev;
    const float* rowp = base + (size_t)(m0 + arow) * 256 + (c & 3) * 64;
    v[0] = *(const float4*)(rowp + q * 8);
    v[1] = *(const float4*)(rowp + q * 8 + 4);
    v[2] = *(const float4*)(rowp + (q + 4) * 8);
    v[3] = *(const float4*)(rowp + (q + 4) * 8 + 4);
  };
  auto wrA = [&](int buf, const float4* v) {
    char* Ab = smem + buf * 8192;
#pragma unroll
    for (int j = 0; j < 2; ++j) {
      int kg = q + 4 * j;
      bf16x8 b;
      b[0] = f2bf(v[2*j].x); b[1] = f2bf(v[2*j].y);
      b[2] = f2bf(v[2*j].z); b[3] = f2bf(v[2*j].w);
      b[4] = f2bf(v[2*j+1].x); b[5] = f2bf(v[2*j+1].y);
      b[6] = f2bf(v[2*j+1].z); b[7] = f2bf(v[2*j+1].w);
      *(bf16x8*)(Ab + kg * 1024 + slotW * 16) = b;
    }
  };
  auto compute = [&](int c, int buf) {
    const char*  Ab = smem + buf * 8192;
    const short* Bc = Bbase + c * 4096;
#pragma unroll
    for (int ks = 0; ks < 4; ++ks) {
      const int kg   = 2 * ks + hh;
      const int slot = (la ^ ((kg & 3) << 2));
      const int off  = kg * 1024 + slot * 16;
      bf16x8 a0 = *(const bf16x8*)(Ab + off);
      bf16x8 a1 = *(const bf16x8*)(Ab + off + 512);   // rows +32
      bf16x8 b0 = *(const bf16x8*)(Bc + ks * 1024);
      bf16x8 b1 = *(const bf16x8*)(Bc + ks * 1024 + 256);
      acc[0][0] = __builtin_amdgcn_mfma_f32_32x32x16_bf16(a0, b0, acc[0][0], 0, 0, 0);
      acc[0][1] = __builtin_amdgcn_mfma_f32_32x32x16_bf16(a0, b1, acc[0][1], 0, 0, 0);
      acc[1][0] = __builtin_amdgcn_mfma_f32_32x32x16_bf16(a1, b0, acc[1][0], 0, 0, 0);
      acc[1][1] = __builtin_amdgcn_mfma_f32_32x32x16_bf16(a1, b1, acc[1][1], 0, 0, 0);
    }
  };

  // ---- pipelined K loop (T14: load-early / write-late) ----
  {
    float4 v[4];
    ldA(0, v); wrA(0, v);
  }
  __syncthreads();
  int buf = 0;
  for (int c = 0; c < NCHUNK; ++c) {
    float4 nv[4];
    if (c + 1 < NCHUNK) ldA(c + 1, nv);     // issue global loads first
    compute(c, buf);                        // MFMA + LDS reads + B L2 reads
    if (c + 1 < NCHUNK) wrA(buf ^ 1, nv);   // cvt + ds_write after compute
    __syncthreads();
    buf ^= 1;
  }

  // ---- epilogue: bias + activation -> LDS exchange (bf16 [4][64][GPAD]) ----
  const float* bptr = (g == 0) ? bfp : (g == 1) ? bip : (g == 2) ? bcp : bop;
  const float bias0 = bptr[n0 + la];
  const float bias1 = bptr[n0 + 32 + la];
  short* G = (short*)smem;
#pragma unroll
  for (int mi = 0; mi < 2; ++mi)
#pragma unroll
    for (int ni = 0; ni < 2; ++ni) {
      const float bias = ni ? bias1 : bias0;
#pragma unroll
      for (int r = 0; r < 16; ++r) {
        int row = (r & 3) + 8 * (r >> 2) + 4 * hh + mi * 32;
        int col = la + ni * 32;
        float v = acc[mi][ni][r] + bias;
        float a;
        if (g == 2) a = 1.f - 2.f / (__expf(2.f * v) + 1.f);   // tanh
        else        a = 1.f / (1.f + __expf(-v));              // sigmoid
        G[(g * 64 + row) * GPAD + col] = f2bf(a);
      }
    }
  __syncthreads();

  // ---- combine + store: thread t -> row t>>2, 16 cols at (t&3)*16 ----
  {
    const int vrow = tid >> 2;
    const int cq   = tid & 3;
    const size_t gi = (size_t)(m0 + vrow) * 256 + n0 + cq * 16;
    float4 cp[4];
#pragma unroll
    for (int i = 0; i < 4; ++i) cp[i] = *(const float4*)(cprev + gi + i * 4);

    bf16x8 gf[4][2];
#pragma unroll
    for (int gg = 0; gg < 4; ++gg) {
      const short* Gr = G + (gg * 64 + vrow) * GPAD + cq * 16;
      gf[gg][0] = *(const bf16x8*)(Gr);
      gf[gg][1] = *(const bf16x8*)(Gr + 8);
    }
    float ho[16], co[16];
#pragma unroll
    for (int e = 0; e < 16; ++e) {
      float fg = bf2f(gf[0][e >> 3][e & 7]);
      float ig = bf2f(gf[1][e >> 3][e & 7]);
      float cg = bf2f(gf[2][e >> 3][e & 7]);
      float og = bf2f(gf[3][e >> 3][e & 7]);
      float cpv = ((const float*)cp)[e];
      float cnew = fg * cpv + ig * cg;
      float hnew = og * (1.f - 2.f / (__expf(2.f * cnew) + 1.f));
      co[e] = cnew; ho[e] = hnew;
    }
#pragma unroll
    for (int i = 0; i < 4; ++i) {
      *(float4*)(hout + gi + i * 4) = ((const float4*)ho)[i];
      *(float4*)(cout + gi + i * 4) = ((const float4*)co)[i];
    }
  }
}

extern "C" void kernel_launch(void* const* d_in, const int* in_sizes, int n_in,
                              void* d_out, int out_size, void* d_ws, size_t ws_size,
                              hipStream_t stream) {
  const float* x     = (const float*)d_in[0];
  const float* hprev = (const float*)d_in[1];
  const float* cprev = (const float*)d_in[2];
  const float* Wf    = (const float*)d_in[3];
  const float* Wi    = (const float*)d_in[4];
  const float* Wc    = (const float*)d_in[5];
  const float* Wo    = (const float*)d_in[6];
  const float* bfp   = (const float*)d_in[7];
  const float* bip   = (const float*)d_in[8];
  const float* bcp   = (const float*)d_in[9];
  const float* bop   = (const float*)d_in[10];
  float* out = (float*)d_out;
  short* Wt  = (short*)d_ws;     // 4*4*32768 bf16 = 1 MB scratch

  cvt_weights<<<2048, 256, 0, stream>>>(Wf, Wi, Wc, Wo, Wt);

  lstm_fused<<<dim3(4096), dim3(256), SMEM_BYTES, stream>>>(
      x, hprev, cprev, Wt, bfp, bip, bcp, bop,
      out, out + (size_t)BATCH * UNITS);
}

// Round 3
// 149.224 us; speedup vs baseline: 1.9562x; 1.0774x over previous
//
#include <hip/hip_runtime.h>
#include <hip/hip_bf16.h>
#include <stdint.h>

#define BATCH   65536
#define UNITS   256
#define NCHUNK  8
#define ROWP    72                     // shorts per column in gate buffer
#define GSZ     (64 * ROWP)            // 4608 shorts per gate
#define SMEM_BYTES 36864               // max(A dbuf 16384, G 4*GSZ*2 = 36864)

using f32x16 = __attribute__((ext_vector_type(16))) float;
using bf16x8 = __attribute__((ext_vector_type(8))) short;

__device__ __forceinline__ short f2bf(float f) {
  union { float f; unsigned u; } v; v.f = f;
  unsigned r = v.u + 0x7FFFu + ((v.u >> 16) & 1u);   // RNE (prepass only)
  return (short)(r >> 16);
}
__device__ __forceinline__ float bf2f(short s) {
  union { float f; unsigned u; } v; v.u = ((unsigned)(unsigned short)s) << 16;
  return v.f;
}
__device__ __forceinline__ unsigned pk2(float a, float b) {   // v_cvt_pk_bf16_f32
  union { __hip_bfloat162 h; unsigned u; } cv;
  cv.h = __float22bfloat162_rn(make_float2(a, b));
  return cv.u;
}
__device__ __forceinline__ bf16x8 cvt8(float4 a, float4 b) {
  union { unsigned u[4]; bf16x8 v; } r;
  r.u[0] = pk2(a.x, a.y); r.u[1] = pk2(a.z, a.w);
  r.u[2] = pk2(b.x, b.y); r.u[3] = pk2(b.z, b.w);
  return r.v;
}

#define BAR() do { asm volatile("s_waitcnt lgkmcnt(0)" ::: "memory"); \
                   __builtin_amdgcn_s_barrier(); } while (0)

// ---- prepass: W_g fp32 [512][256] -> Wt bf16 tiled [g][nb][c][kg][n][k8]
__global__ void cvt_weights(const float* __restrict__ Wf, const float* __restrict__ Wi,
                            const float* __restrict__ Wc, const float* __restrict__ Wo,
                            short* __restrict__ Wt) {
  int idx = blockIdx.x * 256 + threadIdx.x;
  int g   = idx >> 17;
  int k   = (idx >> 8) & 511;
  int col = idx & 255;
  const float* W = (g == 0) ? Wf : (g == 1) ? Wi : (g == 2) ? Wc : Wo;
  float val = W[k * 256 + col];
  int nb = col >> 6, n = col & 63;
  int c = k >> 6, kg = (k >> 3) & 7, k8 = k & 7;
  int out = ((((g * 4 + nb) * 8 + c) * 8 + kg) * 64 + n) * 8 + k8;
  Wt[out] = f2bf(val);
}

// ---- fused LSTM cell: 4 waves/block, wave = gate; A staged in LDS (dbuf),
// B prefetched one chunk ahead into registers; counted-wait barriers.
__global__ __launch_bounds__(256, 3) void lstm_fused(
    const float* __restrict__ x, const float* __restrict__ hprev,
    const float* __restrict__ cprev, const short* __restrict__ Wt,
    const float* __restrict__ bfp, const float* __restrict__ bip,
    const float* __restrict__ bcp, const float* __restrict__ bop,
    float* __restrict__ hout, float* __restrict__ cout)
{
  extern __shared__ __align__(16) char smem[];
  const int tid  = threadIdx.x;
  const int g    = tid >> 6;           // wave = gate
  const int lane = tid & 63;
  const int la   = lane & 31;
  const int hh   = lane >> 5;

  int bid = blockIdx.x;
  int wg  = (bid & 7) * 512 + (bid >> 3);      // XCD-bijective swizzle
  const int m0 = (wg >> 2) * 64;
  const int nb = wg & 3;
  const int n0 = nb * 64;

  const short* Bbase = Wt + ((size_t)(g * 4 + nb)) * 32768 + hh * 512 + la * 8;

  f32x16 acc[2][2] = {};
  bf16x8 breg[8];

  const int arow  = tid >> 2;
  const int q     = tid & 3;
  const int slotW = (arow ^ (q << 2)) & 63;

  auto ldA = [&](int c, float4* v) {
    const float* base = (c < 4) ? x : hprev;
    const float* rowp = base + (size_t)(m0 + arow) * 256 + (c & 3) * 64;
    v[0] = *(const float4*)(rowp + q * 8);
    v[1] = *(const float4*)(rowp + q * 8 + 4);
    v[2] = *(const float4*)(rowp + (q + 4) * 8);
    v[3] = *(const float4*)(rowp + (q + 4) * 8 + 4);
  };
  auto wrA = [&](int buf, const float4* v) {
    char* Ab = smem + buf * 8192;
    *(bf16x8*)(Ab + q * 1024 + slotW * 16)       = cvt8(v[0], v[1]);
    *(bf16x8*)(Ab + (q + 4) * 1024 + slotW * 16) = cvt8(v[2], v[3]);
  };
  auto loadB = [&](int c, int ks) {
    const short* Bc = Bbase + (size_t)c * 4096 + ks * 1024;
    breg[2 * ks]     = *(const bf16x8*)(Bc);
    breg[2 * ks + 1] = *(const bf16x8*)(Bc + 256);
  };

  // ---- prologue ----
  float4 v[4];
  ldA(0, v); wrA(0, v);                // stage chunk 0
  ldA(1, v);                           // A(1) in flight
#pragma unroll
  for (int ks = 0; ks < 4; ++ks) loadB(0, ks);
  BAR();

  // ---- pipelined K loop ----
  int buf = 0;
  for (int c = 0; c < NCHUNK; ++c) {
    if (c + 1 < NCHUNK) wrA(buf ^ 1, v);       // A(c+1): loads issued 1 iter ago
    if (c + 2 < NCHUNK) ldA(c + 2, v);         // issue A(c+2)
    const char*  Ab = smem + buf * 8192;
    const short* Bn = Bbase + (size_t)((c + 1) & 7) * 4096;
#pragma unroll
    for (int ks = 0; ks < 4; ++ks) {
      const int kg   = 2 * ks + hh;
      const int slot = la ^ ((kg & 3) << 2);
      const int off  = kg * 1024 + slot * 16;
      bf16x8 a0 = *(const bf16x8*)(Ab + off);
      bf16x8 a1 = *(const bf16x8*)(Ab + off + 512);
      acc[0][0] = __builtin_amdgcn_mfma_f32_32x32x16_bf16(a0, breg[2*ks],   acc[0][0], 0, 0, 0);
      acc[0][1] = __builtin_amdgcn_mfma_f32_32x32x16_bf16(a0, breg[2*ks+1], acc[0][1], 0, 0, 0);
      acc[1][0] = __builtin_amdgcn_mfma_f32_32x32x16_bf16(a1, breg[2*ks],   acc[1][0], 0, 0, 0);
      acc[1][1] = __builtin_amdgcn_mfma_f32_32x32x16_bf16(a1, breg[2*ks+1], acc[1][1], 0, 0, 0);
      breg[2*ks]     = *(const bf16x8*)(Bn + ks * 1024);        // prefetch c+1
      breg[2*ks + 1] = *(const bf16x8*)(Bn + ks * 1024 + 256);
    }
    BAR();                             // lgkmcnt(0)+s_barrier; vmcnt stays live
    buf ^= 1;
  }

  // ---- epilogue: bias+activation -> transposed gate buffer [g][col][row+ROWP]
  const float* bptr = (g == 0) ? bfp : (g == 1) ? bip : (g == 2) ? bcp : bop;
  const float bias0 = bptr[n0 + la];
  const float bias1 = bptr[n0 + 32 + la];
  short* G = (short*)smem;
#pragma unroll
  for (int mi = 0; mi < 2; ++mi)
#pragma unroll
    for (int ni = 0; ni < 2; ++ni) {
      const float bias = ni ? bias1 : bias0;
      const int   col  = la + ni * 32;
#pragma unroll
      for (int rq = 0; rq < 4; ++rq) {
        const int row0 = rq * 8 + 4 * hh + mi * 32;
        float t[4];
#pragma unroll
        for (int e = 0; e < 4; ++e) {
          float vv = acc[mi][ni][rq * 4 + e] + bias;
          t[e] = (g == 2) ? (1.f - 2.f / (__expf(2.f * vv) + 1.f))   // tanh
                          : (1.f / (1.f + __expf(-vv)));             // sigmoid
        }
        uint2 u; u.x = pk2(t[0], t[1]); u.y = pk2(t[2], t[3]);
        *(uint2*)(G + g * GSZ + col * ROWP + row0) = u;
      }
    }
  BAR();

  // ---- combine + store: thread -> col = tid&63, rows rg*16..+15 ----
  {
    const int col = tid & 63;
    const int rg  = tid >> 6;
    const short* Gp = G + col * ROWP + rg * 16;
    bf16x8 gf[4][2];
#pragma unroll
    for (int gg = 0; gg < 4; ++gg) {
      gf[gg][0] = *(const bf16x8*)(Gp + gg * GSZ);
      gf[gg][1] = *(const bf16x8*)(Gp + gg * GSZ + 8);
    }
    const size_t gbase = (size_t)(m0 + rg * 16) * 256 + n0 + col;
    float cp[16];
#pragma unroll
    for (int j = 0; j < 16; ++j) cp[j] = cprev[gbase + (size_t)j * 256];
#pragma unroll
    for (int j = 0; j < 16; ++j) {
      float fg = bf2f(gf[0][j >> 3][j & 7]);
      float ig = bf2f(gf[1][j >> 3][j & 7]);
      float cg = bf2f(gf[2][j >> 3][j & 7]);
      float og = bf2f(gf[3][j >> 3][j & 7]);
      float cnew = fg * cp[j] + ig * cg;
      float hnew = og * (1.f - 2.f / (__expf(2.f * cnew) + 1.f));
      hout[gbase + (size_t)j * 256] = hnew;
      cout[gbase + (size_t)j * 256] = cnew;
    }
  }
}

extern "C" void kernel_launch(void* const* d_in, const int* in_sizes, int n_in,
                              void* d_out, int out_size, void* d_ws, size_t ws_size,
                              hipStream_t stream) {
  const float* x     = (const float*)d_in[0];
  const float* hprev = (const float*)d_in[1];
  const float* cprev = (const float*)d_in[2];
  const float* Wf    = (const float*)d_in[3];
  const float* Wi    = (const float*)d_in[4];
  const float* Wc    = (const float*)d_in[5];
  const float* Wo    = (const float*)d_in[6];
  const float* bfp   = (const float*)d_in[7];
  const float* bip   = (const float*)d_in[8];
  const float* bcp   = (const float*)d_in[9];
  const float* bop   = (const float*)d_in[10];
  float* out = (float*)d_out;
  short* Wt  = (short*)d_ws;     // 1 MB scratch

  cvt_weights<<<2048, 256, 0, stream>>>(Wf, Wi, Wc, Wo, Wt);

  lstm_fused<<<dim3(4096), dim3(256), SMEM_BYTES, stream>>>(
      x, hprev, cprev, Wt, bfp, bip, bcp, bop,
      out, out + (size_t)BATCH * UNITS);
}